// Round 1
// baseline (724.503 us; speedup 1.0000x reference)
//
#include <hip/hip_runtime.h>
#include <hip/hip_bf16.h>
#include <stdint.h>

#define NN 8192
#define DD 512

typedef unsigned short u16;
typedef __attribute__((ext_vector_type(8))) short short8;
typedef __attribute__((ext_vector_type(4))) float f32x4;

// async global->LDS, 16B per lane; LDS dest = wave-uniform base + lane*16
__device__ __forceinline__ void gld_lds16(const void* g, void* l) {
  __builtin_amdgcn_global_load_lds(
      (const __attribute__((address_space(1))) uint32_t*)(uintptr_t)g,
      (__attribute__((address_space(3))) uint32_t*)(uintptr_t)l,
      16, 0, 0);
}

__device__ __forceinline__ u16 f2bf(float f) {
  __hip_bfloat16 b = __float2bfloat16(f);
  return __builtin_bit_cast(u16, b);
}

__global__ void fill_kernel(float* __restrict__ p, int n, float v) {
  int i = blockIdx.x * 256 + threadIdx.x;
  int stride = gridDim.x * 256;
  for (; i < n; i += stride) p[i] = v;
}

__global__ void cvt4_kernel(const float4* __restrict__ src, ushort4* __restrict__ dst, int n4) {
  int i = blockIdx.x * 256 + threadIdx.x;
  int stride = gridDim.x * 256;
  for (; i < n4; i += stride) {
    float4 v = src[i];
    ushort4 o;
    o.x = f2bf(v.x); o.y = f2bf(v.y); o.z = f2bf(v.z); o.w = f2bf(v.w);
    dst[i] = o;
  }
}

// one wave per row: 1/||Wh_i||
__global__ void rownorm_kernel(const float* __restrict__ Wh, float* __restrict__ invn) {
  int row = blockIdx.x;
  int l = threadIdx.x;  // 64
  const float4* p = (const float4*)(Wh + (size_t)row * DD);
  float4 a = p[l], b = p[l + 64];
  float s = a.x*a.x + a.y*a.y + a.z*a.z + a.w*a.w
          + b.x*b.x + b.y*b.y + b.z*b.z + b.w*b.w;
  #pragma unroll
  for (int off = 32; off; off >>= 1) s += __shfl_down(s, off);
  if (l == 0) invn[row] = 1.0f / sqrtf(s);
}

// 64x64 tile: U = bf16(Wh * invn) (row-major) and WhT = bf16(Wh)^T
__global__ void u_wht_kernel(const float* __restrict__ Wh, const float* __restrict__ invn,
                             u16* __restrict__ U, u16* __restrict__ WhT) {
  __shared__ float tile[64][65];
  int i0 = blockIdx.x * 64, d0 = blockIdx.y * 64;
  int c = threadIdx.x & 63, rb = threadIdx.x >> 6;
  #pragma unroll
  for (int r = rb; r < 64; r += 4) {
    float v = Wh[(size_t)(i0 + r) * DD + d0 + c];
    tile[r][c] = v;
    U[(size_t)(i0 + r) * DD + d0 + c] = f2bf(v * invn[i0 + r]);
  }
  __syncthreads();
  #pragma unroll
  for (int r = rb; r < 64; r += 4) {
    WhT[(size_t)(d0 + r) * NN + i0 + c] = f2bf(tile[c][r]);
  }
}

// den[i] = sum_j P[i][j]
__global__ void rowsum_kernel(const u16* __restrict__ P, float* __restrict__ den) {
  int row = blockIdx.x;
  int tid = threadIdx.x;  // 256
  const uint4* p = (const uint4*)(P + (size_t)row * NN);
  float s = 0.f;
  #pragma unroll
  for (int c = tid; c < NN / 8; c += 256) {
    uint4 u = p[c];
    s += __uint_as_float(u.x << 16) + __uint_as_float(u.x & 0xffff0000u);
    s += __uint_as_float(u.y << 16) + __uint_as_float(u.y & 0xffff0000u);
    s += __uint_as_float(u.z << 16) + __uint_as_float(u.z & 0xffff0000u);
    s += __uint_as_float(u.w << 16) + __uint_as_float(u.w & 0xffff0000u);
  }
  #pragma unroll
  for (int off = 32; off; off >>= 1) s += __shfl_down(s, off);
  __shared__ float partial[4];
  if ((tid & 63) == 0) partial[tid >> 6] = s;
  __syncthreads();
  if (tid == 0) den[row] = partial[0] + partial[1] + partial[2] + partial[3];
}

// C = A * B^T, A:[M x K] row-major bf16, B:[Nn x K] row-major bf16.
// 128x128 tile, BK=32, 256 threads (4 waves, each a 64x64 quadrant).
// MODE 0: store fp32 Cf.  MODE 1: P = mask ? exp(C) : 0, bf16.  MODE 2: Out = C / den[i], fp32.
template <int MODE>
__global__ void __launch_bounds__(256) gemm_bt(
    const u16* __restrict__ A, const u16* __restrict__ B,
    int M, int Nn, int K,
    float* __restrict__ Cf,
    const int* __restrict__ adj, u16* __restrict__ Pb,
    const float* __restrict__ den, float* __restrict__ Out)
{
  __shared__ __align__(16) u16 As[128 * 32];
  __shared__ __align__(16) u16 Bs[128 * 32];

  const int tid = threadIdx.x;
  const int w = tid >> 6;       // wave 0..3 (uniform)
  const int lane = tid & 63;
  const int lm = lane & 15;
  const int q = lane >> 4;
  const int row0 = blockIdx.y * 128;
  const int col0 = blockIdx.x * 128;
  const int RM = (w >> 1) * 64;
  const int RN = (w & 1) * 64;

  const int sr = tid >> 2;        // staging row 0..63
  const int sk = (tid & 3) * 8;   // staging k-offset (elements)

  f32x4 acc[4][4];
  #pragma unroll
  for (int a_ = 0; a_ < 4; a_++)
    #pragma unroll
    for (int b_ = 0; b_ < 4; b_++)
      acc[a_][b_] = (f32x4){0.f, 0.f, 0.f, 0.f};

  const size_t Abase = (size_t)row0 * K;
  const size_t Bbase = (size_t)col0 * K;

  for (int k0 = 0; k0 < K; k0 += 32) {
    __syncthreads();  // previous compute done before overwrite
    gld_lds16(A + Abase + (size_t)sr * K + k0 + sk,        (char*)As + w * 1024);
    gld_lds16(A + Abase + (size_t)(sr + 64) * K + k0 + sk, (char*)As + 4096 + w * 1024);
    gld_lds16(B + Bbase + (size_t)sr * K + k0 + sk,        (char*)Bs + w * 1024);
    gld_lds16(B + Bbase + (size_t)(sr + 64) * K + k0 + sk, (char*)Bs + 4096 + w * 1024);
    __syncthreads();  // compiler emits vmcnt(0) drain before barrier

    short8 af[4], bfr[4];
    #pragma unroll
    for (int mt = 0; mt < 4; mt++)
      af[mt] = *(const short8*)&As[(RM + mt * 16 + lm) * 32 + q * 8];
    #pragma unroll
    for (int nt = 0; nt < 4; nt++)
      bfr[nt] = *(const short8*)&Bs[(RN + nt * 16 + lm) * 32 + q * 8];

    #pragma unroll
    for (int mt = 0; mt < 4; mt++)
      #pragma unroll
      for (int nt = 0; nt < 4; nt++)
        acc[mt][nt] = __builtin_amdgcn_mfma_f32_16x16x32_bf16(af[mt], bfr[nt], acc[mt][nt], 0, 0, 0);
  }

  // C/D layout: col = lane&15, row = q*4 + reg
  #pragma unroll
  for (int mt = 0; mt < 4; mt++) {
    const int ib = row0 + RM + mt * 16 + q * 4;
    #pragma unroll
    for (int rr = 0; rr < 4; rr++) {
      const int i = ib + rr;
      float dinv = 1.0f;
      if (MODE == 2) dinv = 1.0f / den[i];
      #pragma unroll
      for (int nt = 0; nt < 4; nt++) {
        const int jc = col0 + RN + nt * 16 + lm;
        const float v = acc[mt][nt][rr];
        if (MODE == 0) {
          Cf[(size_t)i * Nn + jc] = v;
        } else if (MODE == 1) {
          const int av = adj[(size_t)i * NN + jc];
          const float p = (av > 0 || i == jc) ? __expf(v) : 0.0f;
          Pb[(size_t)i * NN + jc] = f2bf(p);
        } else {
          Out[(size_t)i * Nn + jc] = v * dinv;
        }
      }
    }
  }
}

extern "C" void kernel_launch(void* const* d_in, const int* in_sizes, int n_in,
                              void* d_out, int out_size, void* d_ws, size_t ws_size,
                              hipStream_t stream) {
  const float* h = (const float*)d_in[0];
  const int* adj = (const int*)d_in[1];
  const float* W = (const float*)d_in[2];
  float* out = (float*)d_out;

  // workspace layout
  const size_t SZ_P   = (size_t)NN * NN * 2;   // 134217728
  const size_t SZ_WH  = (size_t)NN * DD * 4;   // 16777216
  const size_t SZ_BF  = (size_t)NN * DD * 2;   // 8388608
  const size_t SZ_WB  = (size_t)DD * DD * 2;   // 524288
  const size_t NEEDED = SZ_P + SZ_WH + 3 * SZ_BF + SZ_WB + 2 * (size_t)NN * 4;

  if (ws_size < NEEDED) {
    // sentinel so a too-small workspace is distinguishable from a math bug
    fill_kernel<<<256, 256, 0, stream>>>(out, out_size, 12345.0f);
    return;
  }

  char* ws = (char*)d_ws;
  u16*   P    = (u16*)(ws);
  float* Wh   = (float*)(ws + SZ_P);
  u16*   U    = (u16*)(ws + SZ_P + SZ_WH);
  u16*   WhT  = (u16*)(ws + SZ_P + SZ_WH + SZ_BF);
  u16*   hb   = (u16*)(ws + SZ_P + SZ_WH + 2 * SZ_BF);
  u16*   Wb   = (u16*)(ws + SZ_P + SZ_WH + 3 * SZ_BF);
  float* invn = (float*)(ws + SZ_P + SZ_WH + 3 * SZ_BF + SZ_WB);
  float* den  = invn + NN;

  // 1) bf16 casts
  cvt4_kernel<<<1024, 256, 0, stream>>>((const float4*)h, (ushort4*)hb, NN * DD / 4);
  cvt4_kernel<<<256, 256, 0, stream>>>((const float4*)W, (ushort4*)Wb, DD * DD / 4);
  // 2) Wh = h @ W^T   (W is [out,in] row-major = B^T form already)
  gemm_bt<0><<<dim3(DD / 128, NN / 128), 256, 0, stream>>>(
      hb, Wb, NN, DD, DD, Wh, nullptr, nullptr, nullptr, nullptr);
  // 3) row norms
  rownorm_kernel<<<NN, 64, 0, stream>>>(Wh, invn);
  // 4) U (unit rows, bf16) + WhT (transposed bf16 for PV B-operand)
  u_wht_kernel<<<dim3(NN / 64, DD / 64), 256, 0, stream>>>(Wh, invn, U, WhT);
  // 5) P = mask ? exp(U U^T) : 0   (bf16, materialized)
  gemm_bt<1><<<dim3(NN / 128, NN / 128), 256, 0, stream>>>(
      U, U, NN, NN, DD, nullptr, adj, P, nullptr, nullptr);
  // 6) den = rowsum(P)  (exactly consistent with P used for numerator)
  rowsum_kernel<<<NN, 256, 0, stream>>>(P, den);
  // 7) out = (P @ WhT^T) / den
  gemm_bt<2><<<dim3(DD / 128, NN / 128), 256, 0, stream>>>(
      P, WhT, NN, DD, NN, nullptr, nullptr, nullptr, den, out);
}

// Round 2
// 707.344 us; speedup vs baseline: 1.0243x; 1.0243x over previous
//
#include <hip/hip_runtime.h>
#include <hip/hip_bf16.h>
#include <stdint.h>

#define NN 8192
#define DD 512

typedef unsigned short u16;
typedef unsigned long long u64;
typedef __attribute__((ext_vector_type(8))) short short8;
typedef __attribute__((ext_vector_type(4))) float f32x4;

// async global->LDS, 16B per lane; LDS dest = wave-uniform base + lane*16
__device__ __forceinline__ void gld_lds16(const void* g, void* l) {
  __builtin_amdgcn_global_load_lds(
      (const __attribute__((address_space(1))) uint32_t*)(uintptr_t)g,
      (__attribute__((address_space(3))) uint32_t*)(uintptr_t)l,
      16, 0, 0);
}

__device__ __forceinline__ u16 f2bf(float f) {
  __hip_bfloat16 b = __float2bfloat16(f);
  return __builtin_bit_cast(u16, b);
}

__global__ void fill_kernel(float* __restrict__ p, int n, float v) {
  int i = blockIdx.x * 256 + threadIdx.x;
  int stride = gridDim.x * 256;
  for (; i < n; i += stride) p[i] = v;
}

__global__ void cvt4_kernel(const float4* __restrict__ src, ushort4* __restrict__ dst, int n4) {
  int i = blockIdx.x * 256 + threadIdx.x;
  int stride = gridDim.x * 256;
  for (; i < n4; i += stride) {
    float4 v = src[i];
    ushort4 o;
    o.x = f2bf(v.x); o.y = f2bf(v.y); o.z = f2bf(v.z); o.w = f2bf(v.w);
    dst[i] = o;
  }
}

// adj (int32 0/1, NN x NN) -> bitmask: u16 per 16 cols; u64 word w of a row has
// bit b = col 64w+b (little-endian u16 packing).
__global__ void pack_adj_kernel(const int* __restrict__ adj, u16* __restrict__ mask) {
  const int row = blockIdx.x;
  const int t = threadIdx.x;
  const uint4* arow = (const uint4*)(adj + (size_t)row * NN);
  #pragma unroll
  for (int iter = 0; iter < 2; iter++) {
    const int c16 = iter * 256 + t;        // u16 index within row (0..511)
    unsigned int bits = 0;
    #pragma unroll
    for (int g = 0; g < 4; g++) {
      uint4 v = arow[c16 * 4 + g];
      bits |= (v.x ? 1u : 0u) << (g * 4 + 0);
      bits |= (v.y ? 1u : 0u) << (g * 4 + 1);
      bits |= (v.z ? 1u : 0u) << (g * 4 + 2);
      bits |= (v.w ? 1u : 0u) << (g * 4 + 3);
    }
    mask[(size_t)row * (NN / 16) + c16] = (u16)bits;
  }
}

// one wave per row: 1/||Wh_i||
__global__ void rownorm_kernel(const float* __restrict__ Wh, float* __restrict__ invn) {
  int row = blockIdx.x;
  int l = threadIdx.x;  // 64
  const float4* p = (const float4*)(Wh + (size_t)row * DD);
  float4 a = p[l], b = p[l + 64];
  float s = a.x*a.x + a.y*a.y + a.z*a.z + a.w*a.w
          + b.x*b.x + b.y*b.y + b.z*b.z + b.w*b.w;
  #pragma unroll
  for (int off = 32; off; off >>= 1) s += __shfl_down(s, off);
  if (l == 0) invn[row] = 1.0f / sqrtf(s);
}

// 64x64 tile: U = bf16(Wh * invn) (row-major) and WhT = bf16(Wh)^T
__global__ void u_wht_kernel(const float* __restrict__ Wh, const float* __restrict__ invn,
                             u16* __restrict__ U, u16* __restrict__ WhT) {
  __shared__ float tile[64][65];
  int i0 = blockIdx.x * 64, d0 = blockIdx.y * 64;
  int c = threadIdx.x & 63, rb = threadIdx.x >> 6;
  #pragma unroll
  for (int r = rb; r < 64; r += 4) {
    float v = Wh[(size_t)(i0 + r) * DD + d0 + c];
    tile[r][c] = v;
    U[(size_t)(i0 + r) * DD + d0 + c] = f2bf(v * invn[i0 + r]);
  }
  __syncthreads();
  #pragma unroll
  for (int r = rb; r < 64; r += 4) {
    WhT[(size_t)(d0 + r) * NN + i0 + c] = f2bf(tile[c][r]);
  }
}

// out = (out + part1) * (1/den[row]); float4 units
__global__ void reduce_scale_kernel(float4* __restrict__ out, const float4* __restrict__ part1,
                                    const float* __restrict__ den) {
  int i4 = blockIdx.x * 256 + threadIdx.x;          // NN*DD/4 units
  const int row = i4 >> 7;                          // 128 float4 per row
  const float dinv = 1.0f / den[row];
  float4 a = out[i4], b = part1[i4];
  a.x = (a.x + b.x) * dinv;
  a.y = (a.y + b.y) * dinv;
  a.z = (a.z + b.z) * dinv;
  a.w = (a.w + b.w) * dinv;
  out[i4] = a;
}

// C = A * B^T, A:[M x K] row-major bf16, B:[Nn x K] row-major bf16.
// 128x128 tile, BK=32, 256 threads (4 waves, each a 64x64 quadrant).
// MODE 0: fp32 store; splitK via blockIdx.z: z=0 -> Cf0 over K[0,kSplit), z=1 -> Cf1 over [kSplit,K).
// MODE 1: P = mask ? exp(C) : 0 -> bf16, + den[i] atomic rowsum (K full).
template <int MODE>
__global__ void __launch_bounds__(256) gemm_bt(
    const u16* __restrict__ A, const u16* __restrict__ B,
    int Nn, int K, int kSplit,
    float* __restrict__ Cf0, float* __restrict__ Cf1,
    const u64* __restrict__ maskw, u16* __restrict__ Pb,
    float* __restrict__ den)
{
  __shared__ __align__(16) u16 As[128 * 32];
  __shared__ __align__(16) u16 Bs[128 * 32];

  const int tid = threadIdx.x;
  const int w = tid >> 6;
  const int lane = tid & 63;
  const int lm = lane & 15;
  const int q = lane >> 4;
  const int row0 = blockIdx.y * 128;
  const int col0 = blockIdx.x * 128;
  const int RM = (w >> 1) * 64;
  const int RN = (w & 1) * 64;

  const int sr = tid >> 2;
  const int sk = (tid & 3) * 8;

  int kBegin = 0, kEnd = K;
  if (MODE == 0) {
    kBegin = blockIdx.z ? kSplit : 0;
    kEnd   = blockIdx.z ? K : kSplit;
  }

  f32x4 acc[4][4];
  #pragma unroll
  for (int a_ = 0; a_ < 4; a_++)
    #pragma unroll
    for (int b_ = 0; b_ < 4; b_++)
      acc[a_][b_] = (f32x4){0.f, 0.f, 0.f, 0.f};

  const size_t Abase = (size_t)row0 * K;
  const size_t Bbase = (size_t)col0 * K;

  for (int k0 = kBegin; k0 < kEnd; k0 += 32) {
    __syncthreads();
    gld_lds16(A + Abase + (size_t)sr * K + k0 + sk,        (char*)As + w * 1024);
    gld_lds16(A + Abase + (size_t)(sr + 64) * K + k0 + sk, (char*)As + 4096 + w * 1024);
    gld_lds16(B + Bbase + (size_t)sr * K + k0 + sk,        (char*)Bs + w * 1024);
    gld_lds16(B + Bbase + (size_t)(sr + 64) * K + k0 + sk, (char*)Bs + 4096 + w * 1024);
    __syncthreads();

    short8 af[4], bfr[4];
    #pragma unroll
    for (int mt = 0; mt < 4; mt++)
      af[mt] = *(const short8*)&As[(RM + mt * 16 + lm) * 32 + q * 8];
    #pragma unroll
    for (int nt = 0; nt < 4; nt++)
      bfr[nt] = *(const short8*)&Bs[(RN + nt * 16 + lm) * 32 + q * 8];

    #pragma unroll
    for (int mt = 0; mt < 4; mt++)
      #pragma unroll
      for (int nt = 0; nt < 4; nt++)
        acc[mt][nt] = __builtin_amdgcn_mfma_f32_16x16x32_bf16(af[mt], bfr[nt], acc[mt][nt], 0, 0, 0);
  }

  // C/D layout: col = lane&15, row = q*4 + reg
  float* const Cf = (MODE == 0 && blockIdx.z) ? Cf1 : Cf0;
  const int wordIdx = (col0 + RN) >> 6;
  #pragma unroll
  for (int mt = 0; mt < 4; mt++) {
    const int ib = row0 + RM + mt * 16 + q * 4;
    #pragma unroll
    for (int rr = 0; rr < 4; rr++) {
      const int i = ib + rr;
      if (MODE == 0) {
        #pragma unroll
        for (int nt = 0; nt < 4; nt++) {
          const int jc = col0 + RN + nt * 16 + lm;
          Cf[(size_t)i * Nn + jc] = acc[mt][nt][rr];
        }
      } else {
        const u64 wrd = maskw[(size_t)i * (NN / 64) + wordIdx];
        float psum = 0.f;
        #pragma unroll
        for (int nt = 0; nt < 4; nt++) {
          const int jc = col0 + RN + nt * 16 + lm;
          const bool on = ((wrd >> (nt * 16 + lm)) & 1ull) || (i == jc);
          const float p = on ? __expf(acc[mt][nt][rr]) : 0.0f;
          psum += p;
          Pb[(size_t)i * NN + jc] = f2bf(p);
        }
        #pragma unroll
        for (int off = 8; off; off >>= 1) psum += __shfl_down(psum, off, 16);
        if (lm == 0) atomicAdd(&den[i], psum);
      }
    }
  }
}

extern "C" void kernel_launch(void* const* d_in, const int* in_sizes, int n_in,
                              void* d_out, int out_size, void* d_ws, size_t ws_size,
                              hipStream_t stream) {
  const float* h = (const float*)d_in[0];
  const int* adj = (const int*)d_in[1];
  const float* W = (const float*)d_in[2];
  float* out = (float*)d_out;

  const size_t SZ_P    = (size_t)NN * NN * 2;
  const size_t SZ_MASK = (size_t)NN * NN / 8;
  const size_t SZ_WHT  = (size_t)DD * NN * 2;
  const size_t SZ_HB   = (size_t)NN * DD * 2;
  const size_t SZ_WB   = (size_t)DD * DD * 2;
  const size_t SZ_U    = (size_t)NN * DD * 2;
  const size_t SZ_WH   = (size_t)NN * DD * 4;   // fp32; reused as split-K part1
  const size_t NEEDED  = SZ_P + SZ_MASK + SZ_WHT + SZ_HB + SZ_WB + SZ_U + SZ_WH + 2 * (size_t)NN * 4;

  if (ws_size < NEEDED) {
    fill_kernel<<<256, 256, 0, stream>>>(out, out_size, 12345.0f);
    return;
  }

  char* ws = (char*)d_ws;
  size_t off = 0;
  u16*   P    = (u16*)(ws + off); off += SZ_P;
  u16*   mask = (u16*)(ws + off); off += SZ_MASK;
  u16*   WhT  = (u16*)(ws + off); off += SZ_WHT;
  u16*   hb   = (u16*)(ws + off); off += SZ_HB;
  u16*   Wb   = (u16*)(ws + off); off += SZ_WB;
  u16*   U    = (u16*)(ws + off); off += SZ_U;
  float* Wh   = (float*)(ws + off); off += SZ_WH;
  float* invn = (float*)(ws + off);
  float* den  = invn + NN;
  float* part1 = Wh;

  pack_adj_kernel<<<NN, 256, 0, stream>>>(adj, mask);
  fill_kernel<<<32, 256, 0, stream>>>(den, NN, 0.0f);
  cvt4_kernel<<<1024, 256, 0, stream>>>((const float4*)h, (ushort4*)hb, NN * DD / 4);
  cvt4_kernel<<<256, 256, 0, stream>>>((const float4*)W, (ushort4*)Wb, DD * DD / 4);
  // Wh = h @ W^T (no split: kSplit = K so z=0 covers all)
  gemm_bt<0><<<dim3(DD / 128, NN / 128, 1), 256, 0, stream>>>(
      hb, Wb, DD, DD, DD, Wh, nullptr, nullptr, nullptr, nullptr);
  rownorm_kernel<<<NN, 64, 0, stream>>>(Wh, invn);
  u_wht_kernel<<<dim3(NN / 64, DD / 64), 256, 0, stream>>>(Wh, invn, U, WhT);
  // P = mask ? exp(U U^T) : 0 + fused den rowsum
  gemm_bt<1><<<dim3(NN / 128, NN / 128, 1), 256, 0, stream>>>(
      U, U, NN, DD, DD, nullptr, nullptr, (const u64*)mask, P, den);
  // out-gemm, split-K=2 via z (z=0: K[0,4096) -> out; z=1: K[4096,8192) -> part1)
  gemm_bt<0><<<dim3(DD / 128, NN / 128, 2), 256, 0, stream>>>(
      P, WhT, DD, NN, NN / 2, out, part1, nullptr, nullptr, nullptr);
  reduce_scale_kernel<<<NN * DD / 4 / 256, 256, 0, stream>>>(
      (float4*)out, (const float4*)part1, den);
}

// Round 3
// 670.864 us; speedup vs baseline: 1.0800x; 1.0544x over previous
//
#include <hip/hip_runtime.h>
#include <hip/hip_bf16.h>
#include <stdint.h>

#define NN 8192
#define DD 512

typedef unsigned short u16;
typedef unsigned long long u64;
typedef __attribute__((ext_vector_type(8))) short short8;
typedef __attribute__((ext_vector_type(4))) float f32x4;

// async global->LDS, 16B per lane; LDS dest = wave-uniform base + lane*16
__device__ __forceinline__ void gld_lds16(const void* g, void* l) {
  __builtin_amdgcn_global_load_lds(
      (const __attribute__((address_space(1))) uint32_t*)(uintptr_t)g,
      (__attribute__((address_space(3))) uint32_t*)(uintptr_t)l,
      16, 0, 0);
}

__device__ __forceinline__ u16 f2bf(float f) {
  __hip_bfloat16 b = __float2bfloat16(f);
  return __builtin_bit_cast(u16, b);
}

__global__ void fill_kernel(float* __restrict__ p, int n, float v) {
  int i = blockIdx.x * 256 + threadIdx.x;
  int stride = gridDim.x * 256;
  for (; i < n; i += stride) p[i] = v;
}

__global__ void cvt4_kernel(const float4* __restrict__ src, ushort4* __restrict__ dst, int n4) {
  int i = blockIdx.x * 256 + threadIdx.x;
  int stride = gridDim.x * 256;
  for (; i < n4; i += stride) {
    float4 v = src[i];
    ushort4 o;
    o.x = f2bf(v.x); o.y = f2bf(v.y); o.z = f2bf(v.z); o.w = f2bf(v.w);
    dst[i] = o;
  }
}

// adj (int32 0/1, NN x NN) -> bitmask: u16 per 16 cols (u64 word w: bit b = col 64w+b)
__global__ void pack_adj_kernel(const int* __restrict__ adj, u16* __restrict__ mask) {
  const int row = blockIdx.x;
  const int t = threadIdx.x;
  const uint4* arow = (const uint4*)(adj + (size_t)row * NN);
  #pragma unroll
  for (int iter = 0; iter < 2; iter++) {
    const int c16 = iter * 256 + t;
    unsigned int bits = 0;
    #pragma unroll
    for (int g = 0; g < 4; g++) {
      uint4 v = arow[c16 * 4 + g];
      bits |= (v.x ? 1u : 0u) << (g * 4 + 0);
      bits |= (v.y ? 1u : 0u) << (g * 4 + 1);
      bits |= (v.z ? 1u : 0u) << (g * 4 + 2);
      bits |= (v.w ? 1u : 0u) << (g * 4 + 3);
    }
    mask[(size_t)row * (NN / 16) + c16] = (u16)bits;
  }
}

// one wave per row: 1/||Wh_i||
__global__ void rownorm_kernel(const float* __restrict__ Wh, float* __restrict__ invn) {
  int row = blockIdx.x;
  int l = threadIdx.x;  // 64
  const float4* p = (const float4*)(Wh + (size_t)row * DD);
  float4 a = p[l], b = p[l + 64];
  float s = a.x*a.x + a.y*a.y + a.z*a.z + a.w*a.w
          + b.x*b.x + b.y*b.y + b.z*b.z + b.w*b.w;
  #pragma unroll
  for (int off = 32; off; off >>= 1) s += __shfl_down(s, off);
  if (l == 0) invn[row] = 1.0f / sqrtf(s);
}

// 64x64 tile: U = bf16(Wh * invn) (row-major) and WhT = bf16(Wh)^T
__global__ void u_wht_kernel(const float* __restrict__ Wh, const float* __restrict__ invn,
                             u16* __restrict__ U, u16* __restrict__ WhT) {
  __shared__ float tile[64][65];
  int i0 = blockIdx.x * 64, d0 = blockIdx.y * 64;
  int c = threadIdx.x & 63, rb = threadIdx.x >> 6;
  #pragma unroll
  for (int r = rb; r < 64; r += 4) {
    float v = Wh[(size_t)(i0 + r) * DD + d0 + c];
    tile[r][c] = v;
    U[(size_t)(i0 + r) * DD + d0 + c] = f2bf(v * invn[i0 + r]);
  }
  __syncthreads();
  #pragma unroll
  for (int r = rb; r < 64; r += 4) {
    WhT[(size_t)(d0 + r) * NN + i0 + c] = f2bf(tile[c][r]);
  }
}

// C = A * B^T, A:[M x K], B:[Nn x K] row-major bf16. 128x128 tile, 256 thr.
// MODE 0: fp32 store to Cf. MODE 1: P = mask ? exp(C) : 0 -> bf16 + den atomic rowsum.
template <int MODE>
__global__ void __launch_bounds__(256) gemm_bt(
    const u16* __restrict__ A, const u16* __restrict__ B,
    int Nn, int K,
    float* __restrict__ Cf,
    const u64* __restrict__ maskw, u16* __restrict__ Pb,
    float* __restrict__ den)
{
  __shared__ __align__(16) u16 As[128 * 32];
  __shared__ __align__(16) u16 Bs[128 * 32];

  const int tid = threadIdx.x;
  const int w = tid >> 6;
  const int lane = tid & 63;
  const int lm = lane & 15;
  const int q = lane >> 4;
  const int row0 = blockIdx.y * 128;
  const int col0 = blockIdx.x * 128;
  const int RM = (w >> 1) * 64;
  const int RN = (w & 1) * 64;

  const int sr = tid >> 2;
  const int sk = (tid & 3) * 8;

  f32x4 acc[4][4];
  #pragma unroll
  for (int a_ = 0; a_ < 4; a_++)
    #pragma unroll
    for (int b_ = 0; b_ < 4; b_++)
      acc[a_][b_] = (f32x4){0.f, 0.f, 0.f, 0.f};

  const size_t Abase = (size_t)row0 * K;
  const size_t Bbase = (size_t)col0 * K;

  for (int k0 = 0; k0 < K; k0 += 32) {
    __syncthreads();
    gld_lds16(A + Abase + (size_t)sr * K + k0 + sk,        (char*)As + w * 1024);
    gld_lds16(A + Abase + (size_t)(sr + 64) * K + k0 + sk, (char*)As + 4096 + w * 1024);
    gld_lds16(B + Bbase + (size_t)sr * K + k0 + sk,        (char*)Bs + w * 1024);
    gld_lds16(B + Bbase + (size_t)(sr + 64) * K + k0 + sk, (char*)Bs + 4096 + w * 1024);
    __syncthreads();

    short8 af[4], bfr[4];
    #pragma unroll
    for (int mt = 0; mt < 4; mt++)
      af[mt] = *(const short8*)&As[(RM + mt * 16 + lm) * 32 + q * 8];
    #pragma unroll
    for (int nt = 0; nt < 4; nt++)
      bfr[nt] = *(const short8*)&Bs[(RN + nt * 16 + lm) * 32 + q * 8];

    #pragma unroll
    for (int mt = 0; mt < 4; mt++)
      #pragma unroll
      for (int nt = 0; nt < 4; nt++)
        acc[mt][nt] = __builtin_amdgcn_mfma_f32_16x16x32_bf16(af[mt], bfr[nt], acc[mt][nt], 0, 0, 0);
  }

  // C/D layout: col = lane&15, row = q*4 + reg
  const int wordIdx = (col0 + RN) >> 6;
  #pragma unroll
  for (int mt = 0; mt < 4; mt++) {
    const int ib = row0 + RM + mt * 16 + q * 4;
    #pragma unroll
    for (int rr = 0; rr < 4; rr++) {
      const int i = ib + rr;
      if (MODE == 0) {
        #pragma unroll
        for (int nt = 0; nt < 4; nt++) {
          const int jc = col0 + RN + nt * 16 + lm;
          Cf[(size_t)i * Nn + jc] = acc[mt][nt][rr];
        }
      } else {
        const u64 wrd = maskw[(size_t)i * (NN / 64) + wordIdx];
        float psum = 0.f;
        #pragma unroll
        for (int nt = 0; nt < 4; nt++) {
          const int jc = col0 + RN + nt * 16 + lm;
          const bool on = ((wrd >> (nt * 16 + lm)) & 1ull) || (i == jc);
          const float p = on ? __expf(acc[mt][nt][rr]) : 0.0f;
          psum += p;
          Pb[(size_t)i * NN + jc] = f2bf(p);
        }
        #pragma unroll
        for (int off = 8; off; off >>= 1) psum += __shfl_down(psum, off, 16);
        if (lm == 0) atomicAdd(&den[i], psum);
      }
    }
  }
}

// out-GEMM: tile 128 rows x FULL N=512, 512 threads (8 waves, each 64x128).
// Split-K=4 via blockIdx.y; partial z stored bf16 to part[z]. P read exactly once.
__global__ void __launch_bounds__(512, 2) gemm_out(
    const u16* __restrict__ A,    // P [NN x NN]
    const u16* __restrict__ B,    // WhT [DD x NN]
    u16* const __restrict__* partv_unused, // unused (see args below)
    u16* __restrict__ p0, u16* __restrict__ p1,
    u16* __restrict__ p2, u16* __restrict__ p3)
{
  __shared__ __align__(16) u16 As[128 * 32];   // 8 KB
  __shared__ __align__(16) u16 Bs[512 * 32];   // 32 KB

  const int tid = threadIdx.x;
  const int w = tid >> 6;        // 0..7
  const int lane = tid & 63;
  const int lm = lane & 15;
  const int q = lane >> 4;
  const int row0 = blockIdx.x * 128;
  const int z = blockIdx.y;      // 0..3
  const int RM = (w >> 2) * 64;  // 0/64
  const int RN = (w & 3) * 128;  // 0..384

  const int sr = tid >> 2;       // 0..127
  const int sk = (tid & 3) * 8;

  f32x4 acc[4][8];
  #pragma unroll
  for (int a_ = 0; a_ < 4; a_++)
    #pragma unroll
    for (int b_ = 0; b_ < 8; b_++)
      acc[a_][b_] = (f32x4){0.f, 0.f, 0.f, 0.f};

  const size_t Abase = (size_t)row0 * NN;
  const int kBegin = z * (NN / 4), kEnd = (z + 1) * (NN / 4);

  for (int k0 = kBegin; k0 < kEnd; k0 += 32) {
    __syncthreads();
    // A-tile: 128x32 = 8 KB = one 512-lane call (per-wave base w*1024)
    gld_lds16(A + Abase + (size_t)sr * NN + k0 + sk, (char*)As + w * 1024);
    // B-tile: 512x32 = 32 KB = four calls
    #pragma unroll
    for (int c = 0; c < 4; c++)
      gld_lds16(B + (size_t)(c * 128 + sr) * NN + k0 + sk, (char*)Bs + c * 8192 + w * 1024);
    __syncthreads();

    short8 af[4], bfr[8];
    #pragma unroll
    for (int mt = 0; mt < 4; mt++)
      af[mt] = *(const short8*)&As[(RM + mt * 16 + lm) * 32 + q * 8];
    #pragma unroll
    for (int nt = 0; nt < 8; nt++)
      bfr[nt] = *(const short8*)&Bs[(RN + nt * 16 + lm) * 32 + q * 8];

    #pragma unroll
    for (int mt = 0; mt < 4; mt++)
      #pragma unroll
      for (int nt = 0; nt < 8; nt++)
        acc[mt][nt] = __builtin_amdgcn_mfma_f32_16x16x32_bf16(af[mt], bfr[nt], acc[mt][nt], 0, 0, 0);
  }

  u16* const part = (z == 0) ? p0 : (z == 1) ? p1 : (z == 2) ? p2 : p3;
  #pragma unroll
  for (int mt = 0; mt < 4; mt++) {
    const int ib = row0 + RM + mt * 16 + q * 4;
    #pragma unroll
    for (int rr = 0; rr < 4; rr++) {
      const int i = ib + rr;
      #pragma unroll
      for (int nt = 0; nt < 8; nt++) {
        const int dc = RN + nt * 16 + lm;
        part[(size_t)i * DD + dc] = f2bf(acc[mt][nt][rr]);
      }
    }
  }
}

// out = (sum of 4 bf16 partials) / den[row]; each thread handles 8 cols
__global__ void reduce4_kernel(const uint4* __restrict__ p0, const uint4* __restrict__ p1,
                               const uint4* __restrict__ p2, const uint4* __restrict__ p3,
                               const float* __restrict__ den, float4* __restrict__ out) {
  const int idx = blockIdx.x * 256 + threadIdx.x;   // NN*DD/8 units of 8 cols
  const int row = idx >> 6;                          // 64 units per row
  const float dinv = 1.0f / den[row];
  float s[8] = {0, 0, 0, 0, 0, 0, 0, 0};
  #pragma unroll
  for (int zp = 0; zp < 4; zp++) {
    const uint4 u = (zp == 0 ? p0 : zp == 1 ? p1 : zp == 2 ? p2 : p3)[idx];
    s[0] += __uint_as_float(u.x << 16); s[1] += __uint_as_float(u.x & 0xffff0000u);
    s[2] += __uint_as_float(u.y << 16); s[3] += __uint_as_float(u.y & 0xffff0000u);
    s[4] += __uint_as_float(u.z << 16); s[5] += __uint_as_float(u.z & 0xffff0000u);
    s[6] += __uint_as_float(u.w << 16); s[7] += __uint_as_float(u.w & 0xffff0000u);
  }
  float4 o0 = {s[0] * dinv, s[1] * dinv, s[2] * dinv, s[3] * dinv};
  float4 o1 = {s[4] * dinv, s[5] * dinv, s[6] * dinv, s[7] * dinv};
  out[idx * 2] = o0;
  out[idx * 2 + 1] = o1;
}

extern "C" void kernel_launch(void* const* d_in, const int* in_sizes, int n_in,
                              void* d_out, int out_size, void* d_ws, size_t ws_size,
                              hipStream_t stream) {
  const float* h = (const float*)d_in[0];
  const int* adj = (const int*)d_in[1];
  const float* W = (const float*)d_in[2];
  float* out = (float*)d_out;

  const size_t SZ_P    = (size_t)NN * NN * 2;
  const size_t SZ_MASK = (size_t)NN * NN / 8;
  const size_t SZ_WHT  = (size_t)DD * NN * 2;
  const size_t SZ_HB   = (size_t)NN * DD * 2;
  const size_t SZ_WB   = (size_t)DD * DD * 2;
  const size_t SZ_U    = (size_t)NN * DD * 2;
  const size_t SZ_WH   = (size_t)NN * DD * 4;
  const size_t NEEDED  = SZ_P + SZ_MASK + SZ_WHT + SZ_HB + SZ_WB + SZ_U + SZ_WH + 2 * (size_t)NN * 4;

  if (ws_size < NEEDED) {
    fill_kernel<<<256, 256, 0, stream>>>(out, out_size, 12345.0f);
    return;
  }

  char* ws = (char*)d_ws;
  size_t off = 0;
  u16*   P    = (u16*)(ws + off); off += SZ_P;
  u16*   mask = (u16*)(ws + off); off += SZ_MASK;
  u16*   WhT  = (u16*)(ws + off); off += SZ_WHT;
  u16*   hb   = (u16*)(ws + off); off += SZ_HB;
  u16*   Wb   = (u16*)(ws + off); off += SZ_WB;
  u16*   U    = (u16*)(ws + off); off += SZ_U;
  float* Wh   = (float*)(ws + off); off += SZ_WH;
  float* invn = (float*)(ws + off);
  float* den  = invn + NN;

  // split-K partials (bf16) reuse regions dead after the sim-GEMM:
  u16* part0 = U;                 // U dead after sim-gemm
  u16* part1 = hb;                // hb dead after Wh-gemm
  u16* part2 = (u16*)Wh;          // Wh fp32 dead after u_wht (holds 2 bf16 partials)
  u16* part3 = (u16*)Wh + (size_t)NN * DD;

  pack_adj_kernel<<<NN, 256, 0, stream>>>(adj, mask);
  fill_kernel<<<32, 256, 0, stream>>>(den, NN, 0.0f);
  cvt4_kernel<<<1024, 256, 0, stream>>>((const float4*)h, (ushort4*)hb, NN * DD / 4);
  cvt4_kernel<<<256, 256, 0, stream>>>((const float4*)W, (ushort4*)Wb, DD * DD / 4);
  // Wh = h @ W^T
  gemm_bt<0><<<dim3(DD / 128, NN / 128), 256, 0, stream>>>(
      hb, Wb, DD, DD, Wh, nullptr, nullptr, nullptr);
  rownorm_kernel<<<NN, 64, 0, stream>>>(Wh, invn);
  u_wht_kernel<<<dim3(NN / 64, DD / 64), 256, 0, stream>>>(Wh, invn, U, WhT);
  // P = mask ? exp(U U^T) : 0 (bf16) + fused den rowsum
  gemm_bt<1><<<dim3(NN / 128, NN / 128), 256, 0, stream>>>(
      U, U, NN, DD, nullptr, (const u64*)mask, P, den);
  // out partials: full-N tile, split-K=4 (P read exactly once)
  gemm_out<<<dim3(NN / 128, 4), 512, 0, stream>>>(
      P, WhT, nullptr, part0, part1, part2, part3);
  // out = (p0+p1+p2+p3) / den
  reduce4_kernel<<<NN * DD / 8 / 256, 256, 0, stream>>>(
      (const uint4*)part0, (const uint4*)part1, (const uint4*)part2, (const uint4*)part3,
      den, (float4*)out);
}

// Round 4
// 649.775 us; speedup vs baseline: 1.1150x; 1.0325x over previous
//
#include <hip/hip_runtime.h>
#include <hip/hip_bf16.h>
#include <stdint.h>

#define NN 8192
#define DD 512

typedef unsigned short u16;
typedef unsigned long long u64;
typedef __attribute__((ext_vector_type(8))) short short8;
typedef __attribute__((ext_vector_type(4))) float f32x4;

// async global->LDS, 16B per lane; LDS dest = wave-uniform base + lane*16
__device__ __forceinline__ void gld_lds16(const void* g, void* l) {
  __builtin_amdgcn_global_load_lds(
      (const __attribute__((address_space(1))) uint32_t*)(uintptr_t)g,
      (__attribute__((address_space(3))) uint32_t*)(uintptr_t)l,
      16, 0, 0);
}

__device__ __forceinline__ u16 f2bf(float f) {
  __hip_bfloat16 b = __float2bfloat16(f);
  return __builtin_bit_cast(u16, b);
}

__global__ void fill_kernel(float* __restrict__ p, int n, float v) {
  int i = blockIdx.x * 256 + threadIdx.x;
  int stride = gridDim.x * 256;
  for (; i < n; i += stride) p[i] = v;
}

__global__ void cvt4_kernel(const float4* __restrict__ src, ushort4* __restrict__ dst, int n4) {
  int i = blockIdx.x * 256 + threadIdx.x;
  int stride = gridDim.x * 256;
  for (; i < n4; i += stride) {
    float4 v = src[i];
    ushort4 o;
    o.x = f2bf(v.x); o.y = f2bf(v.y); o.z = f2bf(v.z); o.w = f2bf(v.w);
    dst[i] = o;
  }
}

// adj (int32 0/1, NN x NN) -> bitmask: u16 per 16 cols (u64 word w: bit b = col 64w+b)
// Also zeroes den[row] (one per block) - saves a launch.
__global__ void pack_adj_kernel(const int* __restrict__ adj, u16* __restrict__ mask,
                                float* __restrict__ den) {
  const int row = blockIdx.x;
  const int t = threadIdx.x;
  if (t == 0) den[row] = 0.0f;
  const uint4* arow = (const uint4*)(adj + (size_t)row * NN);
  #pragma unroll
  for (int iter = 0; iter < 2; iter++) {
    const int c16 = iter * 256 + t;
    unsigned int bits = 0;
    #pragma unroll
    for (int g = 0; g < 4; g++) {
      uint4 v = arow[c16 * 4 + g];
      bits |= (v.x ? 1u : 0u) << (g * 4 + 0);
      bits |= (v.y ? 1u : 0u) << (g * 4 + 1);
      bits |= (v.z ? 1u : 0u) << (g * 4 + 2);
      bits |= (v.w ? 1u : 0u) << (g * 4 + 3);
    }
    mask[(size_t)row * (NN / 16) + c16] = (u16)bits;
  }
}

// one wave per row: 1/||Wh_i||
__global__ void rownorm_kernel(const float* __restrict__ Wh, float* __restrict__ invn) {
  int row = blockIdx.x;
  int l = threadIdx.x;  // 64
  const float4* p = (const float4*)(Wh + (size_t)row * DD);
  float4 a = p[l], b = p[l + 64];
  float s = a.x*a.x + a.y*a.y + a.z*a.z + a.w*a.w
          + b.x*b.x + b.y*b.y + b.z*b.z + b.w*b.w;
  #pragma unroll
  for (int off = 32; off; off >>= 1) s += __shfl_down(s, off);
  if (l == 0) invn[row] = 1.0f / sqrtf(s);
}

// 64x64 tile: U = bf16(Wh * invn) (row-major) and WhT = bf16(Wh)^T
__global__ void u_wht_kernel(const float* __restrict__ Wh, const float* __restrict__ invn,
                             u16* __restrict__ U, u16* __restrict__ WhT) {
  __shared__ float tile[64][65];
  int i0 = blockIdx.x * 64, d0 = blockIdx.y * 64;
  int c = threadIdx.x & 63, rb = threadIdx.x >> 6;
  #pragma unroll
  for (int r = rb; r < 64; r += 4) {
    float v = Wh[(size_t)(i0 + r) * DD + d0 + c];
    tile[r][c] = v;
    U[(size_t)(i0 + r) * DD + d0 + c] = f2bf(v * invn[i0 + r]);
  }
  __syncthreads();
  #pragma unroll
  for (int r = rb; r < 64; r += 4) {
    WhT[(size_t)(d0 + r) * NN + i0 + c] = f2bf(tile[c][r]);
  }
}

// Wh-GEMM: C = A * B^T fp32, A:[M x K], B:[Nn x K] bf16. 128x128 tile, 256 thr.
__global__ void __launch_bounds__(256) gemm_wh(
    const u16* __restrict__ A, const u16* __restrict__ B,
    int Nn, int K, float* __restrict__ Cf)
{
  __shared__ __align__(16) u16 As[128 * 32];
  __shared__ __align__(16) u16 Bs[128 * 32];

  const int tid = threadIdx.x;
  const int w = tid >> 6;
  const int lane = tid & 63;
  const int lm = lane & 15;
  const int q = lane >> 4;
  const int row0 = blockIdx.y * 128;
  const int col0 = blockIdx.x * 128;
  const int RM = (w >> 1) * 64;
  const int RN = (w & 1) * 64;
  const int sr = tid >> 2;
  const int sk = (tid & 3) * 8;

  f32x4 acc[4][4];
  #pragma unroll
  for (int a_ = 0; a_ < 4; a_++)
    #pragma unroll
    for (int b_ = 0; b_ < 4; b_++)
      acc[a_][b_] = (f32x4){0.f, 0.f, 0.f, 0.f};

  const size_t Abase = (size_t)row0 * K;
  const size_t Bbase = (size_t)col0 * K;

  for (int k0 = 0; k0 < K; k0 += 32) {
    __syncthreads();
    gld_lds16(A + Abase + (size_t)sr * K + k0 + sk,        (char*)As + w * 1024);
    gld_lds16(A + Abase + (size_t)(sr + 64) * K + k0 + sk, (char*)As + 4096 + w * 1024);
    gld_lds16(B + Bbase + (size_t)sr * K + k0 + sk,        (char*)Bs + w * 1024);
    gld_lds16(B + Bbase + (size_t)(sr + 64) * K + k0 + sk, (char*)Bs + 4096 + w * 1024);
    __syncthreads();

    short8 af[4], bfr[4];
    #pragma unroll
    for (int mt = 0; mt < 4; mt++)
      af[mt] = *(const short8*)&As[(RM + mt * 16 + lm) * 32 + q * 8];
    #pragma unroll
    for (int nt = 0; nt < 4; nt++)
      bfr[nt] = *(const short8*)&Bs[(RN + nt * 16 + lm) * 32 + q * 8];

    #pragma unroll
    for (int mt = 0; mt < 4; mt++)
      #pragma unroll
      for (int nt = 0; nt < 4; nt++)
        acc[mt][nt] = __builtin_amdgcn_mfma_f32_16x16x32_bf16(af[mt], bfr[nt], acc[mt][nt], 0, 0, 0);
  }

  #pragma unroll
  for (int mt = 0; mt < 4; mt++) {
    const int ib = row0 + RM + mt * 16 + q * 4;
    #pragma unroll
    for (int rr = 0; rr < 4; rr++) {
      const int i = ib + rr;
      #pragma unroll
      for (int nt = 0; nt < 4; nt++) {
        const int jc = col0 + RN + nt * 16 + lm;
        Cf[(size_t)i * Nn + jc] = acc[mt][nt][rr];
      }
    }
  }
}

// Symmetric sim-GEMM: S = U U^T computed only for lower-tri 128x128 blocks
// (bi >= bj, 2080 blocks). Each off-diag block writes P[i][j] (normal) and
// P[j][i] (mirror, ushort4-coalesced along rows) + den atomics for both sides.
__global__ void __launch_bounds__(256) gemm_sim(
    const u16* __restrict__ U, const u64* __restrict__ maskw,
    u16* __restrict__ Pb, float* __restrict__ den)
{
  __shared__ __align__(16) u16 As[128 * 32];
  __shared__ __align__(16) u16 Bs[128 * 32];

  // decode linear block index -> lower-tri (bi, bj), bi >= bj
  const int b = blockIdx.x;
  int bi = (int)((sqrtf(8.0f * (float)b + 1.0f) - 1.0f) * 0.5f);
  while ((bi + 1) * (bi + 2) / 2 <= b) bi++;
  while (bi * (bi + 1) / 2 > b) bi--;
  const int bj = b - bi * (bi + 1) / 2;

  const int tid = threadIdx.x;
  const int w = tid >> 6;
  const int lane = tid & 63;
  const int lm = lane & 15;
  const int q = lane >> 4;
  const int row0 = bi * 128;
  const int col0 = bj * 128;
  const int RM = (w >> 1) * 64;
  const int RN = (w & 1) * 64;
  const int sr = tid >> 2;
  const int sk = (tid & 3) * 8;
  const bool diag = (bi == bj);

  f32x4 acc[4][4];
  #pragma unroll
  for (int a_ = 0; a_ < 4; a_++)
    #pragma unroll
    for (int b_ = 0; b_ < 4; b_++)
      acc[a_][b_] = (f32x4){0.f, 0.f, 0.f, 0.f};

  const size_t Abase = (size_t)row0 * DD;
  const size_t Bbase = (size_t)col0 * DD;

  for (int k0 = 0; k0 < DD; k0 += 32) {
    __syncthreads();
    gld_lds16(U + Abase + (size_t)sr * DD + k0 + sk,        (char*)As + w * 1024);
    gld_lds16(U + Abase + (size_t)(sr + 64) * DD + k0 + sk, (char*)As + 4096 + w * 1024);
    gld_lds16(U + Bbase + (size_t)sr * DD + k0 + sk,        (char*)Bs + w * 1024);
    gld_lds16(U + Bbase + (size_t)(sr + 64) * DD + k0 + sk, (char*)Bs + 4096 + w * 1024);
    __syncthreads();

    short8 af[4], bfr[4];
    #pragma unroll
    for (int mt = 0; mt < 4; mt++)
      af[mt] = *(const short8*)&As[(RM + mt * 16 + lm) * 32 + q * 8];
    #pragma unroll
    for (int nt = 0; nt < 4; nt++)
      bfr[nt] = *(const short8*)&Bs[(RN + nt * 16 + lm) * 32 + q * 8];

    #pragma unroll
    for (int mt = 0; mt < 4; mt++)
      #pragma unroll
      for (int nt = 0; nt < 4; nt++)
        acc[mt][nt] = __builtin_amdgcn_mfma_f32_16x16x32_bf16(af[mt], bfr[nt], acc[mt][nt], 0, 0, 0);
  }

  // C/D layout: col = lane&15 (lm), row = q*4 + reg (rr)
  const int wordIdx = (col0 + RN) >> 6;        // mask word for normal side
  const int word2Idx = (row0 + RM) >> 6;       // mask word for mirror side

  // preload mirror mask words (per nt; uniform across mt/rr/q)
  u64 wrd2[4];
  if (!diag) {
    #pragma unroll
    for (int nt = 0; nt < 4; nt++) {
      const int jc = col0 + RN + nt * 16 + lm;
      wrd2[nt] = maskw[(size_t)jc * (NN / 64) + word2Idx];
    }
  }

  float msum[4] = {0.f, 0.f, 0.f, 0.f};

  #pragma unroll
  for (int mt = 0; mt < 4; mt++) {
    const int ib = row0 + RM + mt * 16 + q * 4;
    float pm[4][4];  // [nt][rr] mirror values
    #pragma unroll
    for (int rr = 0; rr < 4; rr++) {
      const int i = ib + rr;
      const u64 wrd = maskw[(size_t)i * (NN / 64) + wordIdx];
      const int bit2 = mt * 16 + q * 4 + rr;   // == i & 63
      float psum = 0.f;
      #pragma unroll
      for (int nt = 0; nt < 4; nt++) {
        const int jc = col0 + RN + nt * 16 + lm;
        const float ev = __expf(acc[mt][nt][rr]);
        const bool on = ((wrd >> (nt * 16 + lm)) & 1ull) || (diag && i == jc);
        const float p = on ? ev : 0.0f;
        psum += p;
        Pb[(size_t)i * NN + jc] = f2bf(p);
        if (!diag) {
          const bool on2 = (wrd2[nt] >> bit2) & 1ull;
          const float pmv = on2 ? ev : 0.0f;
          pm[nt][rr] = pmv;
          msum[nt] += pmv;
        }
      }
      #pragma unroll
      for (int off = 8; off; off >>= 1) psum += __shfl_down(psum, off, 16);
      if (lm == 0) atomicAdd(&den[i], psum);
    }
    if (!diag) {
      #pragma unroll
      for (int nt = 0; nt < 4; nt++) {
        const int jc = col0 + RN + nt * 16 + lm;
        ushort4 m4;
        m4.x = f2bf(pm[nt][0]); m4.y = f2bf(pm[nt][1]);
        m4.z = f2bf(pm[nt][2]); m4.w = f2bf(pm[nt][3]);
        *(ushort4*)&Pb[(size_t)jc * NN + ib] = m4;
      }
    }
  }

  if (!diag) {
    #pragma unroll
    for (int nt = 0; nt < 4; nt++) {
      float s = msum[nt];
      s += __shfl_xor(s, 16);
      s += __shfl_xor(s, 32);
      if (q == 0) atomicAdd(&den[col0 + RN + nt * 16 + lm], s);
    }
  }
}

// out-GEMM: tile 128 rows x FULL N=512, 512 threads (8 waves, each 64x128).
// Split-K=4 via blockIdx.y; partial z stored bf16. P read exactly once.
__global__ void __launch_bounds__(512, 2) gemm_out(
    const u16* __restrict__ A,    // P [NN x NN]
    const u16* __restrict__ B,    // WhT [DD x NN]
    u16* __restrict__ p0, u16* __restrict__ p1,
    u16* __restrict__ p2, u16* __restrict__ p3)
{
  __shared__ __align__(16) u16 As[128 * 32];   // 8 KB
  __shared__ __align__(16) u16 Bs[512 * 32];   // 32 KB

  const int tid = threadIdx.x;
  const int w = tid >> 6;        // 0..7
  const int lane = tid & 63;
  const int lm = lane & 15;
  const int q = lane >> 4;
  const int row0 = blockIdx.x * 128;
  const int z = blockIdx.y;      // 0..3
  const int RM = (w >> 2) * 64;  // 0/64
  const int RN = (w & 3) * 128;  // 0..384
  const int sr = tid >> 2;       // 0..127
  const int sk = (tid & 3) * 8;

  f32x4 acc[4][8];
  #pragma unroll
  for (int a_ = 0; a_ < 4; a_++)
    #pragma unroll
    for (int b_ = 0; b_ < 8; b_++)
      acc[a_][b_] = (f32x4){0.f, 0.f, 0.f, 0.f};

  const size_t Abase = (size_t)row0 * NN;
  const int kBegin = z * (NN / 4), kEnd = (z + 1) * (NN / 4);

  for (int k0 = kBegin; k0 < kEnd; k0 += 32) {
    __syncthreads();
    gld_lds16(A + Abase + (size_t)sr * NN + k0 + sk, (char*)As + w * 1024);
    #pragma unroll
    for (int c = 0; c < 4; c++)
      gld_lds16(B + (size_t)(c * 128 + sr) * NN + k0 + sk, (char*)Bs + c * 8192 + w * 1024);
    __syncthreads();

    short8 af[4], bfr[8];
    #pragma unroll
    for (int mt = 0; mt < 4; mt++)
      af[mt] = *(const short8*)&As[(RM + mt * 16 + lm) * 32 + q * 8];
    #pragma unroll
    for (int nt = 0; nt < 8; nt++)
      bfr[nt] = *(const short8*)&Bs[(RN + nt * 16 + lm) * 32 + q * 8];

    #pragma unroll
    for (int mt = 0; mt < 4; mt++)
      #pragma unroll
      for (int nt = 0; nt < 8; nt++)
        acc[mt][nt] = __builtin_amdgcn_mfma_f32_16x16x32_bf16(af[mt], bfr[nt], acc[mt][nt], 0, 0, 0);
  }

  u16* const part = (z == 0) ? p0 : (z == 1) ? p1 : (z == 2) ? p2 : p3;
  #pragma unroll
  for (int mt = 0; mt < 4; mt++) {
    const int ib = row0 + RM + mt * 16 + q * 4;
    #pragma unroll
    for (int rr = 0; rr < 4; rr++) {
      const int i = ib + rr;
      #pragma unroll
      for (int nt = 0; nt < 8; nt++) {
        const int dc = RN + nt * 16 + lm;
        part[(size_t)i * DD + dc] = f2bf(acc[mt][nt][rr]);
      }
    }
  }
}

// out = (sum of 4 bf16 partials) / den[row]; each thread handles 8 cols
__global__ void reduce4_kernel(const uint4* __restrict__ p0, const uint4* __restrict__ p1,
                               const uint4* __restrict__ p2, const uint4* __restrict__ p3,
                               const float* __restrict__ den, float4* __restrict__ out) {
  const int idx = blockIdx.x * 256 + threadIdx.x;   // NN*DD/8 units of 8 cols
  const int row = idx >> 6;                          // 64 units per row
  const float dinv = 1.0f / den[row];
  float s[8] = {0, 0, 0, 0, 0, 0, 0, 0};
  #pragma unroll
  for (int zp = 0; zp < 4; zp++) {
    const uint4 u = (zp == 0 ? p0 : zp == 1 ? p1 : zp == 2 ? p2 : p3)[idx];
    s[0] += __uint_as_float(u.x << 16); s[1] += __uint_as_float(u.x & 0xffff0000u);
    s[2] += __uint_as_float(u.y << 16); s[3] += __uint_as_float(u.y & 0xffff0000u);
    s[4] += __uint_as_float(u.z << 16); s[5] += __uint_as_float(u.z & 0xffff0000u);
    s[6] += __uint_as_float(u.w << 16); s[7] += __uint_as_float(u.w & 0xffff0000u);
  }
  float4 o0 = {s[0] * dinv, s[1] * dinv, s[2] * dinv, s[3] * dinv};
  float4 o1 = {s[4] * dinv, s[5] * dinv, s[6] * dinv, s[7] * dinv};
  out[idx * 2] = o0;
  out[idx * 2 + 1] = o1;
}

extern "C" void kernel_launch(void* const* d_in, const int* in_sizes, int n_in,
                              void* d_out, int out_size, void* d_ws, size_t ws_size,
                              hipStream_t stream) {
  const float* h = (const float*)d_in[0];
  const int* adj = (const int*)d_in[1];
  const float* W = (const float*)d_in[2];
  float* out = (float*)d_out;

  const size_t SZ_P    = (size_t)NN * NN * 2;      // 134.2 MB
  const size_t SZ_MASK = (size_t)NN * NN / 8;      // 8.4 MB  (-> part0)
  const size_t SZ_WHT  = (size_t)DD * NN * 2;      // 8.4 MB
  const size_t SZ_HB   = (size_t)NN * DD * 2;      // 8.4 MB  (-> part2)
  const size_t SZ_WB   = (size_t)DD * DD * 2;      // 0.5 MB
  const size_t SZ_U    = (size_t)NN * DD * 2;      // 8.4 MB  (-> part1)
  const size_t SZ_P3   = (size_t)NN * DD * 2;      // 8.4 MB  (part3)
  const size_t NEEDED  = SZ_P + SZ_MASK + SZ_WHT + SZ_HB + SZ_WB + SZ_U + SZ_P3 + 2 * (size_t)NN * 4;

  if (ws_size < NEEDED) {
    fill_kernel<<<256, 256, 0, stream>>>(out, out_size, 12345.0f);
    return;
  }

  char* ws = (char*)d_ws;
  size_t off = 0;
  u16*   P    = (u16*)(ws + off); off += SZ_P;
  u16*   mask = (u16*)(ws + off); off += SZ_MASK;
  u16*   WhT  = (u16*)(ws + off); off += SZ_WHT;
  u16*   hb   = (u16*)(ws + off); off += SZ_HB;
  u16*   Wb   = (u16*)(ws + off); off += SZ_WB;
  u16*   U    = (u16*)(ws + off); off += SZ_U;
  u16*   p3   = (u16*)(ws + off); off += SZ_P3;
  float* invn = (float*)(ws + off);
  float* den  = invn + NN;

  // Wh fp32 (16.8 MB) aliases the P prefix: dead before sim writes P.
  float* Wh = (float*)P;
  // split-K partials reuse regions dead after the sim-GEMM:
  u16* part0 = mask;
  u16* part1 = U;
  u16* part2 = hb;
  u16* part3 = p3;

  pack_adj_kernel<<<NN, 256, 0, stream>>>(adj, mask, den);
  cvt4_kernel<<<1024, 256, 0, stream>>>((const float4*)h, (ushort4*)hb, NN * DD / 4);
  cvt4_kernel<<<256, 256, 0, stream>>>((const float4*)W, (ushort4*)Wb, DD * DD / 4);
  // Wh = h @ W^T
  gemm_wh<<<dim3(DD / 128, NN / 128), 256, 0, stream>>>(hb, Wb, DD, DD, Wh);
  rownorm_kernel<<<NN, 64, 0, stream>>>(Wh, invn);
  u_wht_kernel<<<dim3(NN / 64, DD / 64), 256, 0, stream>>>(Wh, invn, U, WhT);
  // P = mask ? exp(U U^T) : 0 (bf16), symmetric lower-tri + mirror, fused den
  gemm_sim<<<64 * 65 / 2, 256, 0, stream>>>(U, (const u64*)mask, P, den);
  // out partials: full-N tile, split-K=4 (P read exactly once)
  gemm_out<<<dim3(NN / 128, 4), 512, 0, stream>>>(P, WhT, part0, part1, part2, part3);
  // out = (p0+p1+p2+p3) / den
  reduce4_kernel<<<NN * DD / 8 / 256, 256, 0, stream>>>(
      (const uint4*)part0, (const uint4*)part1, (const uint4*)part2, (const uint4*)part3,
      den, (float4*)out);
}